// Round 3
// baseline (895.352 us; speedup 1.0000x reference)
//
#include <hip/hip_runtime.h>
#include <hip/hip_bf16.h>

#define NUM_CLASSES 100000
#define NUM_SAMPLED 5000
#define BATCH 4096
#define DIM 1024
#define NPAD 5120   // 5000 padded to 40 tiles of 128

typedef float floatx4 __attribute__((ext_vector_type(4)));
typedef short bf16x8 __attribute__((ext_vector_type(8)));

// ---------------------------------------------------------------- helpers
__device__ __forceinline__ float log_expected_count(int c) {
    // p = log((c+2)/(c+1)) / log(NUM_CLASSES+1)
    float p = log1pf(1.0f / (float)(c + 1)) / logf((float)NUM_CLASSES + 1.0f);
    float t = (float)NUM_SAMPLED * log1pf(-p);
    return logf(-expm1f(t));
}

__device__ __forceinline__ void async_ld16(const void* g, void* l) {
    __builtin_amdgcn_global_load_lds(
        (const __attribute__((address_space(1))) unsigned int*)g,
        (__attribute__((address_space(3))) unsigned int*)l,
        16, 0, 0);
}

// ---------------------------------------------------------------- K1: init maps + rowsum
__global__ __launch_bounds__(256) void init_kernel(int* map_s, int* map_l, float* rowsum) {
    int i = blockIdx.x * 256 + threadIdx.x;
    if (i < NUM_CLASSES) { map_s[i] = 0x7FFFFFFF; map_l[i] = 0x7FFFFFFF; }
    if (i < BATCH) rowsum[i] = 0.0f;
}

// ---------------------------------------------------------------- K2: build first-occurrence maps + sampled shift
__global__ __launch_bounds__(256) void build_kernel(const float* __restrict__ b,
                                                    const int* __restrict__ sampled,
                                                    const int* __restrict__ labels,
                                                    int* map_s, int* map_l,
                                                    float* __restrict__ shift) {
    int id = blockIdx.x * 256 + threadIdx.x;
    if (id < NPAD) {
        if (id < NUM_SAMPLED) {
            int c = sampled[id];
            atomicMin(&map_s[c], id);
            shift[id] = b[c] - log_expected_count(c);
        } else {
            shift[id] = -1e30f;
        }
    } else if (id < NPAD + BATCH) {
        int m = id - NPAD;
        atomicMin(&map_l[labels[m]], m);
    }
}

// ---------------------------------------------------------------- K3: pack maps (low16=sampled dest, high16=label dest; 0xFFFF=none)
__global__ __launch_bounds__(256) void pack_kernel(const int* __restrict__ map_s,
                                                   const int* __restrict__ map_l,
                                                   int* __restrict__ packed) {
    int i = blockIdx.x * 256 + threadIdx.x;
    if (i < NUM_CLASSES) {
        unsigned s = (unsigned)min(map_s[i], 0xFFFF);
        unsigned l = (unsigned)min(map_l[i], 0xFFFF);
        packed[i] = (int)(s | (l << 16));
    }
}

// ---------------------------------------------------------------- K4: x -> bf16
__global__ __launch_bounds__(256) void convert_x_kernel(const float* __restrict__ x,
                                                        __hip_bfloat16* __restrict__ A) {
    int i = (blockIdx.x * 256 + threadIdx.x) * 4;
    float4 v = *reinterpret_cast<const float4*>(x + i);
    union { ushort4 u; __hip_bfloat16 h[4]; } o;
    o.h[0] = __float2bfloat16(v.x);
    o.h[1] = __float2bfloat16(v.y);
    o.h[2] = __float2bfloat16(v.z);
    o.h[3] = __float2bfloat16(v.w);
    *reinterpret_cast<ushort4*>(A + i) = o.u;
}

// ---------------------------------------------------------------- K5: single scan of w -> BT (sampled, first-occ) + LBT (labels, first-occ)
// grid: (ceil(NC/1024)=98, DIM/32=32). Block: 256 thr, thread = 4 consecutive c, 32 k's.
__global__ __launch_bounds__(256) void scan_kernel(const float* __restrict__ w,
                                                   const int* __restrict__ packed,
                                                   __hip_bfloat16* __restrict__ BT,
                                                   __hip_bfloat16* __restrict__ LBT) {
    const int c  = blockIdx.x * 1024 + threadIdx.x * 4;
    const int k0 = blockIdx.y * 32;
    if (c >= NUM_CLASSES) return;
    const bool full = (c + 3 < NUM_CLASSES);

    unsigned pk[4];
    if (full) {
        int4 p = *reinterpret_cast<const int4*>(packed + c);
        pk[0] = (unsigned)p.x; pk[1] = (unsigned)p.y;
        pk[2] = (unsigned)p.z; pk[3] = (unsigned)p.w;
    } else {
        #pragma unroll
        for (int j = 0; j < 4; j++)
            pk[j] = (c + j < NUM_CLASSES) ? (unsigned)packed[c + j] : 0xFFFFFFFFu;
    }

    int sd[4], ld[4];
    bool any = false;
    #pragma unroll
    for (int j = 0; j < 4; j++) {
        unsigned s = pk[j] & 0xFFFFu;
        unsigned l = pk[j] >> 16;
        sd[j] = (s != 0xFFFFu) ? (int)s : -1;
        ld[j] = (l != 0xFFFFu) ? (int)l : -1;
        any |= (sd[j] >= 0) | (ld[j] >= 0);
    }
    if (!any) return;   // ~68% of threads exit; loads below fetch only needed lines

    for (int k = 0; k < 32; k++) {
        const size_t rowoff = (size_t)(k0 + k) * NUM_CLASSES;
        float vv[4];
        if (full) {
            float4 v = *reinterpret_cast<const float4*>(w + rowoff + c);
            vv[0] = v.x; vv[1] = v.y; vv[2] = v.z; vv[3] = v.w;
        } else {
            #pragma unroll
            for (int j = 0; j < 4; j++)
                vv[j] = (c + j < NUM_CLASSES) ? w[rowoff + c + j] : 0.0f;
        }
        #pragma unroll
        for (int j = 0; j < 4; j++) {
            if (sd[j] >= 0) BT [(size_t)sd[j] * DIM + k0 + k] = __float2bfloat16(vv[j]);
            if (ld[j] >= 0) LBT[(size_t)ld[j] * DIM + k0 + k] = __float2bfloat16(vv[j]);
        }
    }
}

// ---------------------------------------------------------------- K6: fix duplicate sampled/label columns (copy first-occurrence row)
// one wave per candidate; grid covers 5000 + 4096 waves
__global__ __launch_bounds__(256) void dupfix_kernel(const int* __restrict__ sampled,
                                                     const int* __restrict__ labels,
                                                     const int* __restrict__ packed,
                                                     __hip_bfloat16* __restrict__ BT,
                                                     __hip_bfloat16* __restrict__ LBT) {
    const int wid  = blockIdx.x * 4 + (threadIdx.x >> 6);
    const int lane = threadIdx.x & 63;
    const __hip_bfloat16* src = nullptr;
    __hip_bfloat16* dst = nullptr;
    if (wid < NUM_SAMPLED) {
        unsigned f = (unsigned)packed[sampled[wid]] & 0xFFFFu;
        if ((int)f != wid) { src = BT + (size_t)f * DIM; dst = BT + (size_t)wid * DIM; }
    } else if (wid < NUM_SAMPLED + BATCH) {
        int m = wid - NUM_SAMPLED;
        unsigned f = (unsigned)packed[labels[m]] >> 16;
        if ((int)f != m) { src = LBT + (size_t)f * DIM; dst = LBT + (size_t)m * DIM; }
    }
    if (dst) {
        // 1024 bf16 = 2048 B = 128 uint4; 64 lanes x 2
        reinterpret_cast<uint4*>(dst)[lane]      = reinterpret_cast<const uint4*>(src)[lane];
        reinterpret_cast<uint4*>(dst)[lane + 64] = reinterpret_cast<const uint4*>(src)[lane + 64];
    }
}

// ---------------------------------------------------------------- K7: GEMM 4096x5120x1024 bf16 + fused exp-rowsum epilogue
#define BM 128
#define BN 128
#define BK 64

__global__ __launch_bounds__(256) void gemm_kernel(const __hip_bfloat16* __restrict__ A,
                                                   const __hip_bfloat16* __restrict__ BT,
                                                   const float* __restrict__ shift,
                                                   float* __restrict__ rowsum) {
    __shared__ __hip_bfloat16 As[BM * BK];
    __shared__ __hip_bfloat16 Bs[BN * BK];

    const int tid  = threadIdx.x;
    const int m0   = blockIdx.x * BM;
    const int n0   = blockIdx.y * BN;
    const int lane = tid & 63;
    const int wv   = tid >> 6;
    const int wm   = (wv >> 1) * 64;
    const int wn   = (wv & 1) * 64;
    const int col  = lane & 15;
    const int quad = lane >> 4;

    floatx4 acc[4][4] = {};

    const __hip_bfloat16* gA[4];
    const __hip_bfloat16* gB[4];
    int ldsOff[4];
    #pragma unroll
    for (int r = 0; r < 4; r++) {
        int eo  = tid * 8 + r * 2048;
        int row = eo >> 6;
        int cl  = eo & 63;
        gA[r] = A  + (size_t)(m0 + row) * DIM + cl;
        gB[r] = BT + (size_t)(n0 + row) * DIM + cl;
        ldsOff[r] = eo;
    }

    for (int kt = 0; kt < DIM; kt += BK) {
        #pragma unroll
        for (int r = 0; r < 4; r++)
            async_ld16(gA[r] + kt, &As[ldsOff[r]]);
        #pragma unroll
        for (int r = 0; r < 4; r++)
            async_ld16(gB[r] + kt, &Bs[ldsOff[r]]);
        __syncthreads();

        #pragma unroll
        for (int ks = 0; ks < 2; ks++) {
            const int kc = ks * 32 + quad * 8;
            bf16x8 af[4], bfr[4];
            #pragma unroll
            for (int i = 0; i < 4; i++) {
                af[i]  = *reinterpret_cast<const bf16x8*>(&As[(wm + i * 16 + col) * BK + kc]);
                bfr[i] = *reinterpret_cast<const bf16x8*>(&Bs[(wn + i * 16 + col) * BK + kc]);
            }
            #pragma unroll
            for (int i = 0; i < 4; i++)
                #pragma unroll
                for (int j = 0; j < 4; j++)
                    acc[i][j] = __builtin_amdgcn_mfma_f32_16x16x32_bf16(af[i], bfr[j], acc[i][j], 0, 0, 0);
        }
        __syncthreads();
    }

    float sh[4];
    #pragma unroll
    for (int j = 0; j < 4; j++)
        sh[j] = shift[n0 + wn + j * 16 + col];

    #pragma unroll
    for (int i = 0; i < 4; i++) {
        #pragma unroll
        for (int r = 0; r < 4; r++) {
            float s = 0.0f;
            #pragma unroll
            for (int j = 0; j < 4; j++)
                s += __expf(acc[i][j][r] + sh[j]);
            s += __shfl_xor(s, 1);
            s += __shfl_xor(s, 2);
            s += __shfl_xor(s, 4);
            s += __shfl_xor(s, 8);
            if (col == 0) {
                int mrow = m0 + wm + i * 16 + quad * 4 + r;
                atomicAdd(&rowsum[mrow], s);
            }
        }
    }
}

// ---------------------------------------------------------------- K8: true logit (paired-row bf16 dot) + per-row loss
__global__ __launch_bounds__(256) void rowloss_kernel(const __hip_bfloat16* __restrict__ A,
                                                      const __hip_bfloat16* __restrict__ LBT,
                                                      const float* __restrict__ b,
                                                      const int* __restrict__ labels,
                                                      const float* __restrict__ rowsum,
                                                      float* __restrict__ rowloss) {
    const int m    = blockIdx.x * 4 + (threadIdx.x >> 6);
    const int lane = threadIdx.x & 63;
    const size_t base = (size_t)m * DIM + lane * 8;

    float p = 0.0f;
    #pragma unroll
    for (int h = 0; h < 2; h++) {
        bf16x8 av = *reinterpret_cast<const bf16x8*>(A   + base + h * 512);
        bf16x8 lv = *reinterpret_cast<const bf16x8*>(LBT + base + h * 512);
        #pragma unroll
        for (int j = 0; j < 8; j++) {
            union { short s; __hip_bfloat16 h16; } ua, ul;
            ua.s = av[j]; ul.s = lv[j];
            p = fmaf(__bfloat162float(ua.h16), __bfloat162float(ul.h16), p);
        }
    }
    #pragma unroll
    for (int off = 32; off > 0; off >>= 1)
        p += __shfl_xor(p, off);

    if (lane == 0) {
        int lbl = labels[m];
        float tl = p + b[lbl] - log_expected_count(lbl);
        rowloss[m] = logf(rowsum[m] + __expf(tl)) - tl;
    }
}

// ---------------------------------------------------------------- K9: mean over rows
__global__ __launch_bounds__(256) void reduce_kernel(const float* __restrict__ rowloss,
                                                     float* __restrict__ out) {
    __shared__ float red[4];
    const int t = threadIdx.x;
    float s = 0.0f;
    #pragma unroll
    for (int i = t; i < BATCH; i += 256)
        s += rowloss[i];
    #pragma unroll
    for (int off = 32; off > 0; off >>= 1)
        s += __shfl_xor(s, off);
    if ((t & 63) == 0) red[t >> 6] = s;
    __syncthreads();
    if (t == 0)
        out[0] = (red[0] + red[1] + red[2] + red[3]) * (1.0f / (float)BATCH);
}

// ---------------------------------------------------------------- launch
extern "C" void kernel_launch(void* const* d_in, const int* in_sizes, int n_in,
                              void* d_out, int out_size, void* d_ws, size_t ws_size,
                              hipStream_t stream) {
    const float* x       = (const float*)d_in[0];
    const float* w       = (const float*)d_in[1];
    const float* b       = (const float*)d_in[2];
    const int*   labels  = (const int*)d_in[3];
    const int*   sampled = (const int*)d_in[4];
    float* out = (float*)d_out;

    char* ws = (char*)d_ws;
    const size_t MB = 1024 * 1024;
    __hip_bfloat16* A      = (__hip_bfloat16*)(ws);            // 8 MB  (4096x1024)
    __hip_bfloat16* BT     = (__hip_bfloat16*)(ws + 8  * MB);  // 10 MB (5120x1024)
    __hip_bfloat16* LBT    = (__hip_bfloat16*)(ws + 18 * MB);  // 8 MB  (4096x1024)
    int*   packed  = (int*)  (ws + 26 * MB);                   // 400 KB
    int*   map_s   = (int*)  (ws + 27 * MB);                   // 400 KB
    int*   map_l   = (int*)  (ws + 28 * MB);                   // 400 KB
    float* shift   = (float*)(ws + 29 * MB);                   // 20 KB
    float* rowsum  = (float*)(ws + 29 * MB + 64 * 1024);       // 16 KB
    float* rowloss = (float*)(ws + 29 * MB + 128 * 1024);      // 16 KB

    hipLaunchKernelGGL(init_kernel, dim3((NUM_CLASSES + 255) / 256), dim3(256), 0, stream,
                       map_s, map_l, rowsum);
    hipLaunchKernelGGL(build_kernel, dim3((NPAD + BATCH + 255) / 256), dim3(256), 0, stream,
                       b, sampled, labels, map_s, map_l, shift);
    hipLaunchKernelGGL(pack_kernel, dim3((NUM_CLASSES + 255) / 256), dim3(256), 0, stream,
                       map_s, map_l, packed);
    hipLaunchKernelGGL(convert_x_kernel, dim3((BATCH * DIM / 4) / 256), dim3(256), 0, stream, x, A);
    hipLaunchKernelGGL(scan_kernel, dim3((NUM_CLASSES + 1023) / 1024, DIM / 32), dim3(256), 0, stream,
                       w, packed, BT, LBT);
    hipLaunchKernelGGL(dupfix_kernel, dim3((NUM_SAMPLED + BATCH + 3) / 4), dim3(256), 0, stream,
                       sampled, labels, packed, BT, LBT);
    hipLaunchKernelGGL(gemm_kernel, dim3(BATCH / BM, NPAD / BN), dim3(256), 0, stream,
                       A, BT, shift, rowsum);
    hipLaunchKernelGGL(rowloss_kernel, dim3(BATCH / 4), dim3(256), 0, stream,
                       A, LBT, b, labels, rowsum, rowloss);
    hipLaunchKernelGGL(reduce_kernel, dim3(1), dim3(256), 0, stream, rowloss, out);
}